// Round 1
// 3145.004 us; speedup vs baseline: 1.6268x; 1.6268x over previous
//
#include <hip/hip_runtime.h>
#include <math.h>

#define WSZ 8
#define SHIFT 4
#define HD 32
#define NH 6
#define CH 192
#define HP 256
#define WP 256
#define NPX 64
#define SCALE 0.17677669529663687f

using bf16x8 = __attribute__((ext_vector_type(8))) short;           // 8 bf16 (4 VGPRs)
using f32x4  = __attribute__((ext_vector_type(4))) float;
using u16x4  = __attribute__((ext_vector_type(4))) unsigned short;
using u16x8  = __attribute__((ext_vector_type(8))) unsigned short;

#define MFMA __builtin_amdgcn_mfma_f32_16x16x32_bf16

__device__ __forceinline__ unsigned short f2bf(float f) {
    unsigned u = __float_as_uint(f);
    u += 0x7fffu + ((u >> 16) & 1u);          // RNE
    return (unsigned short)(u >> 16);
}
__device__ __forceinline__ float bf2f(unsigned short h) {
    return __uint_as_float(((unsigned)h) << 16);
}

// ---------- prep: transpose + hi/lo-split weights into workspace ----------
// ws u16 layout: wqT_h[576][192] | wqT_l[576][192] | woT_h[192][192] | woT_l[192][192]
__global__ void wprep(const float* __restrict__ w_qkv,
                      const float* __restrict__ w_out,
                      unsigned short* __restrict__ ws)
{
    int idx = blockIdx.x * 256 + threadIdx.x;    // 576*256 = 147456 threads exactly
    unsigned short* wqh = ws;
    unsigned short* wql = ws + 110592;
    unsigned short* woh = ws + 221184;
    unsigned short* wol = ws + 258048;
    if (idx < 110592) {
        int n = idx / 192, c = idx % 192;
        float v = w_qkv[c * 576 + n];
        unsigned short h = f2bf(v);
        wqh[idx] = h;
        wql[idx] = f2bf(v - bf2f(h));
    } else {
        int j = idx - 110592;
        int n = j / 192, c = j % 192;
        float v = w_out[c * 192 + n];
        unsigned short h = f2bf(v);
        woh[j] = h;
        wol[j] = f2bf(v - bf2f(h));
    }
}

// ---------- fused W-MSA, MFMA bf16 hi/lo-split (3-term ~= fp32) ----------
// 512 thr = 8 waves. Frags: idx = lane&15, k = (lane>>4)*8+j (contiguous).
// C/D: col = lane&15 (arg2 idx), row = (lane>>4)*4+r (arg1 idx)  [m89-verified].
// Swapped arg order (arg1 = N-side) makes the 4 C values consecutive in memory.
__global__ __launch_bounds__(512)
void wmsa_mfma(const float* __restrict__ x,
               const float* __restrict__ b_qkv,
               const float* __restrict__ rel_pos,
               const float* __restrict__ b_out,
               const unsigned short* __restrict__ ws,
               float* __restrict__ out)
{
    // strides padded to 4-bank row-step (2-way aliasing = free), rows 16B-aligned
    __shared__ __align__(16) unsigned short xa_h[NPX][200];  // x hi; later attn-out hi
    __shared__ __align__(16) unsigned short xa_l[NPX][200];  // x lo; later attn-out lo
    __shared__ __align__(16) unsigned short qS[NPX][40], qL[NPX][40];
    __shared__ __align__(16) unsigned short kS[NPX][40], kL[NPX][40];
    __shared__ __align__(16) unsigned short vS[HD][72],  vL[HD][72];   // v transposed [d][pix]
    __shared__ __align__(16) float          simb[NPX][68];
    __shared__ __align__(16) unsigned short pS[NPX][72], pL[NPX][72];
    // total 116736 B -> 1 block/CU

    const unsigned short* wqh = ws;
    const unsigned short* wql = ws + 110592;
    const unsigned short* woh = ws + 221184;
    const unsigned short* wol = ws + 258048;

    const int t   = threadIdx.x;
    const int blk = blockIdx.x;
    const int b   = blk >> 10;
    const int w   = blk & 1023;
    const int wy  = w >> 5;
    const int wx  = w & 31;

    const int l   = t & 63;
    const int wv  = t >> 6;        // wave 0..7
    const int l15 = l & 15;
    const int lhi = l >> 4;        // 0..3
    const int g   = wv & 1;
    const int mt  = wv >> 1;       // pixel-tile 0..3

    // ---- stage rolled x window -> LDS bf16 hi/lo ----
    #pragma unroll
    for (int i = 0; i < 6; ++i) {
        int idx = t + i * 512;
        int p   = idx / 48;
        int c4  = idx % 48;
        int py = p >> 3, px = p & 7;
        int sy = (wy * WSZ + py + SHIFT) & 255;
        int sx = (wx * WSZ + px + SHIFT) & 255;
        const float4* src = (const float4*)(x + (((size_t)b * HP + sy) * WP + sx) * CH);
        float4 v4 = src[c4];
        float f[4] = {v4.x, v4.y, v4.z, v4.w};
        u16x4 hi, lo;
        #pragma unroll
        for (int j = 0; j < 4; ++j) {
            unsigned short hh = f2bf(f[j]);
            hi[j] = hh;
            lo[j] = f2bf(f[j] - bf2f(hh));
        }
        *(u16x4*)&xa_h[p][c4 * 4] = hi;
        *(u16x4*)&xa_l[p][c4 * 4] = lo;
    }
    __syncthreads();

    const bool edgeY = (wy == 31);
    const bool edgeX = (wx == 31);
    const f32x4 zero4 = {0.f, 0.f, 0.f, 0.f};

    f32x4 att[NH];                 // PV results stashed in regs (head loop unrolled)

    #pragma unroll
    for (int h = 0; h < NH; ++h) {
        // ======== QKV: [64x192] @ wqT -> q,k (row-major) & v (transposed) ========
        {
            f32x4 acc[3] = {zero4, zero4, zero4};
            int wr[3]; int cl[3]; bool isv[3];
            #pragma unroll
            for (int tl = 0; tl < 3; ++tl) {
                int nl = g * 3 + tl;                      // 0..5: q0 q1 k0 | k1 v0 v1
                if (nl < 2)      { wr[tl] = h * 32 + nl * 16;             cl[tl] = nl * 16;       isv[tl] = false; }
                else if (nl < 4) { wr[tl] = 192 + h * 32 + (nl - 2) * 16; cl[tl] = (nl - 2) * 16; isv[tl] = false; }
                else             { wr[tl] = 384 + h * 32 + (nl - 4) * 16; cl[tl] = (nl - 4) * 16; isv[tl] = true;  }
            }
            #pragma unroll
            for (int kc = 0; kc < 6; ++kc) {
                bf16x8 axh = *(const bf16x8*)&xa_h[mt * 16 + l15][kc * 32 + lhi * 8];
                bf16x8 axl = *(const bf16x8*)&xa_l[mt * 16 + l15][kc * 32 + lhi * 8];
                #pragma unroll
                for (int tl = 0; tl < 3; ++tl) {
                    size_t wo = (size_t)(wr[tl] + l15) * 192 + kc * 32 + lhi * 8;
                    bf16x8 bwh = *(const bf16x8*)&wqh[wo];
                    bf16x8 bwl = *(const bf16x8*)&wql[wo];
                    if (!isv[tl]) {            // q/k swapped: C row = out-ch, col = pixel
                        acc[tl] = MFMA(bwh, axh, acc[tl], 0, 0, 0);
                        acc[tl] = MFMA(bwl, axh, acc[tl], 0, 0, 0);
                        acc[tl] = MFMA(bwh, axl, acc[tl], 0, 0, 0);
                    } else {                   // v normal: C row = pixel, col = d
                        acc[tl] = MFMA(axh, bwh, acc[tl], 0, 0, 0);
                        acc[tl] = MFMA(axl, bwh, acc[tl], 0, 0, 0);
                        acc[tl] = MFMA(axh, bwl, acc[tl], 0, 0, 0);
                    }
                }
            }
            #pragma unroll
            for (int tl = 0; tl < 3; ++tl) {
                int nl = g * 3 + tl;
                if (!isv[tl]) {
                    int pix = mt * 16 + l15;
                    int c0  = cl[tl] + lhi * 4;                        // 4 consecutive channels
                    int jb  = (nl < 2 ? h * 32 : 192 + h * 32) + c0;
                    const f32x4 bias = *(const f32x4*)&b_qkv[jb];
                    u16x4 hi, lo;
                    #pragma unroll
                    for (int r = 0; r < 4; ++r) {
                        float v = acc[tl][r] + bias[r];
                        unsigned short hh = f2bf(v);
                        hi[r] = hh; lo[r] = f2bf(v - bf2f(hh));
                    }
                    if (nl < 2) { *(u16x4*)&qS[pix][c0] = hi; *(u16x4*)&qL[pix][c0] = lo; }
                    else        { *(u16x4*)&kS[pix][c0] = hi; *(u16x4*)&kL[pix][c0] = lo; }
                } else {
                    int d    = cl[tl] + l15;
                    int pix0 = mt * 16 + lhi * 4;                      // 4 consecutive pixels
                    float bv = b_qkv[384 + h * 32 + d];
                    u16x4 hi, lo;
                    #pragma unroll
                    for (int r = 0; r < 4; ++r) {
                        float v = acc[tl][r] + bv;
                        unsigned short hh = f2bf(v);
                        hi[r] = hh; lo[r] = f2bf(v - bf2f(hh));
                    }
                    *(u16x4*)&vS[d][pix0] = hi;
                    *(u16x4*)&vL[d][pix0] = lo;
                }
            }
        }
        __syncthreads();

        // ======== QK^T (swapped: arg1=k -> 4 consecutive key cols per lane) ========
        {
            bf16x8 aqh = *(const bf16x8*)&qS[mt * 16 + l15][lhi * 8];
            bf16x8 aql = *(const bf16x8*)&qL[mt * 16 + l15][lhi * 8];
            #pragma unroll
            for (int k2 = 0; k2 < 2; ++k2) {
                int kt = g * 2 + k2;
                bf16x8 bkh = *(const bf16x8*)&kS[kt * 16 + l15][lhi * 8];
                bf16x8 bkl = *(const bf16x8*)&kL[kt * 16 + l15][lhi * 8];
                f32x4 s = zero4;
                s = MFMA(bkh, aqh, s, 0, 0, 0);
                s = MFMA(bkl, aqh, s, 0, 0, 0);
                s = MFMA(bkh, aql, s, 0, 0, 0);
                *(f32x4*)&simb[mt * 16 + l15][kt * 16 + lhi * 4] = s;  // float4 write
            }
        }
        __syncthreads();

        // ======== softmax + bias + shift-mask (proven fp32 path) ========
        {
            const int p  = t >> 3;
            const int qb = (t & 7) * 8;
            const int py = p >> 3, px = p & 7;
            float s[8];
            f32x4 s0 = *(const f32x4*)&simb[p][qb];
            f32x4 s1 = *(const f32x4*)&simb[p][qb + 4];
            #pragma unroll
            for (int i = 0; i < 4; ++i) { s[i] = s0[i]; s[i + 4] = s1[i]; }
            #pragma unroll
            for (int i = 0; i < 8; ++i) {
                int q  = qb + i;
                int qy = q >> 3, qx = q & 7;
                float val = s[i] * SCALE + rel_pos[h * 225 + (py - qy + 7) * 15 + (px - qx + 7)];
                bool msk = (edgeY && ((py < SHIFT) != (qy < SHIFT))) ||
                           (edgeX && ((px < SHIFT) != (qx < SHIFT)));
                s[i] = msk ? -1e30f : val;
            }
            float m = s[0];
            #pragma unroll
            for (int i = 1; i < 8; ++i) m = fmaxf(m, s[i]);
            #pragma unroll
            for (int off = 1; off < 8; off <<= 1) m = fmaxf(m, __shfl_xor(m, off));
            float sum = 0.f;
            #pragma unroll
            for (int i = 0; i < 8; ++i) { s[i] = __expf(s[i] - m); sum += s[i]; }
            #pragma unroll
            for (int off = 1; off < 8; off <<= 1) sum += __shfl_xor(sum, off);
            float inv = 1.f / sum;
            u16x8 hi, lo;
            #pragma unroll
            for (int i = 0; i < 8; ++i) {
                float pv = s[i] * inv;
                unsigned short hh = f2bf(pv);
                hi[i] = hh; lo[i] = f2bf(pv - bf2f(hh));
            }
            *(u16x8*)&pS[p][qb] = hi;                                  // b128 write
            *(u16x8*)&pL[p][qb] = lo;
        }
        __syncthreads();

        // ======== PV (swapped: arg1=vT -> C row=d, col=pixel) -> stash in regs ====
        {
            f32x4 pa = zero4;
            #pragma unroll
            for (int kc = 0; kc < 2; ++kc) {
                bf16x8 avh = *(const bf16x8*)&vS[g * 16 + l15][kc * 32 + lhi * 8];
                bf16x8 avl = *(const bf16x8*)&vL[g * 16 + l15][kc * 32 + lhi * 8];
                bf16x8 bph = *(const bf16x8*)&pS[mt * 16 + l15][kc * 32 + lhi * 8];
                bf16x8 bpl = *(const bf16x8*)&pL[mt * 16 + l15][kc * 32 + lhi * 8];
                pa = MFMA(avh, bph, pa, 0, 0, 0);
                pa = MFMA(avl, bph, pa, 0, 0, 0);
                pa = MFMA(avh, bpl, pa, 0, 0, 0);
            }
            att[h] = pa;
        }
        __syncthreads();           // protects q/k/v/sim/p reuse by next head
    }

    // ---- attn-out -> xa (x is dead now), split hi/lo ----
    {
        int pix = mt * 16 + l15;
        #pragma unroll
        for (int h = 0; h < NH; ++h) {
            int c0 = h * 32 + g * 16 + lhi * 4;
            u16x4 hi, lo;
            #pragma unroll
            for (int r = 0; r < 4; ++r) {
                float v = att[h][r];
                unsigned short hh = f2bf(v);
                hi[r] = hh; lo[r] = f2bf(v - bf2f(hh));
            }
            *(u16x4*)&xa_h[pix][c0] = hi;
            *(u16x4*)&xa_l[pix][c0] = lo;
        }
    }
    __syncthreads();

    // ======== output projection (swapped) + inverse-roll scatter ========
    {
        f32x4 po[6];
        #pragma unroll
        for (int i = 0; i < 6; ++i) po[i] = zero4;
        #pragma unroll
        for (int kc = 0; kc < 6; ++kc) {
            bf16x8 bxh = *(const bf16x8*)&xa_h[mt * 16 + l15][kc * 32 + lhi * 8];
            bf16x8 bxl = *(const bf16x8*)&xa_l[mt * 16 + l15][kc * 32 + lhi * 8];
            #pragma unroll
            for (int tn = 0; tn < 6; ++tn) {
                int nt = g + 2 * tn;
                size_t wo = (size_t)(nt * 16 + l15) * 192 + kc * 32 + lhi * 8;
                bf16x8 awh = *(const bf16x8*)&woh[wo];
                bf16x8 awl = *(const bf16x8*)&wol[wo];
                po[tn] = MFMA(awh, bxh, po[tn], 0, 0, 0);
                po[tn] = MFMA(awl, bxh, po[tn], 0, 0, 0);
                po[tn] = MFMA(awh, bxl, po[tn], 0, 0, 0);
            }
        }
        int pix = mt * 16 + l15;
        int py = pix >> 3, px = pix & 7;
        int sy = (wy * WSZ + py + SHIFT) & 255;
        int sx = (wx * WSZ + px + SHIFT) & 255;
        float* dst = out + (((size_t)b * HP + sy) * WP + sx) * CH;
        #pragma unroll
        for (int tn = 0; tn < 6; ++tn) {
            int nt = g + 2 * tn;
            int c0 = nt * 16 + lhi * 4;
            f32x4 r = po[tn];
            const f32x4 bb = *(const f32x4*)&b_out[c0];
            r += bb;
            *(f32x4*)&dst[c0] = r;                                     // dwordx4 store
        }
    }
}

extern "C" void kernel_launch(void* const* d_in, const int* in_sizes, int n_in,
                              void* d_out, int out_size, void* d_ws, size_t ws_size,
                              hipStream_t stream) {
    const float* x       = (const float*)d_in[0];
    const float* w_qkv   = (const float*)d_in[1];
    const float* b_qkv   = (const float*)d_in[2];
    const float* rel_pos = (const float*)d_in[3];
    const float* w_out   = (const float*)d_in[4];
    const float* b_out   = (const float*)d_in[5];
    unsigned short* ws   = (unsigned short*)d_ws;   // needs 589824 B

    wprep<<<dim3(576), dim3(256), 0, stream>>>(w_qkv, w_out, ws);
    wmsa_mfma<<<dim3(8192), dim3(512), 0, stream>>>(
        x, b_qkv, rel_pos, b_out, ws, (float*)d_out);
}

// Round 2
// 2906.860 us; speedup vs baseline: 1.7601x; 1.0819x over previous
//
#include <hip/hip_runtime.h>
#include <math.h>

#define WSZ 8
#define SHIFT 4
#define HD 32
#define NH 6
#define CH 192
#define HP 256
#define WP 256
#define NPX 64
#define SCALE 0.17677669529663687f

using bf16x8 = __attribute__((ext_vector_type(8))) short;           // 8 bf16 (4 VGPRs)
using f32x4  = __attribute__((ext_vector_type(4))) float;
using u16x4  = __attribute__((ext_vector_type(4))) unsigned short;
using u16x8  = __attribute__((ext_vector_type(8))) unsigned short;
typedef unsigned short ush;

#define MFMA __builtin_amdgcn_mfma_f32_16x16x32_bf16

__device__ __forceinline__ unsigned short f2bf(float f) {
    unsigned u = __float_as_uint(f);
    u += 0x7fffu + ((u >> 16) & 1u);          // RNE
    return (unsigned short)(u >> 16);
}
__device__ __forceinline__ float bf2f(unsigned short h) {
    return __uint_as_float(((unsigned)h) << 16);
}

// ---------- prep: transpose + hi/lo-split weights into workspace ----------
// ws u16 layout: wqT_h[576][192] | wqT_l[576][192] | woT_h[192][192] | woT_l[192][192]
__global__ void wprep(const float* __restrict__ w_qkv,
                      const float* __restrict__ w_out,
                      unsigned short* __restrict__ ws)
{
    int idx = blockIdx.x * 256 + threadIdx.x;    // 576*256 = 147456 threads exactly
    unsigned short* wqh = ws;
    unsigned short* wql = ws + 110592;
    unsigned short* woh = ws + 221184;
    unsigned short* wol = ws + 258048;
    if (idx < 110592) {
        int n = idx / 192, c = idx % 192;
        float v = w_qkv[c * 576 + n];
        unsigned short h = f2bf(v);
        wqh[idx] = h;
        wql[idx] = f2bf(v - bf2f(h));
    } else {
        int j = idx - 110592;
        int n = j / 192, c = j % 192;
        float v = w_out[c * 192 + n];
        unsigned short h = f2bf(v);
        woh[j] = h;
        wol[j] = f2bf(v - bf2f(h));
    }
}

// ---------- fused W-MSA, MFMA bf16 hi/lo-split (3-term ~= fp32) ----------
// 512 thr = 8 waves. x A-fragments are LANE-PRIVATE (pixel = mt*16+l15) ->
// held in 48 VGPRs, loaded straight from global. LDS = 65536 B -> 2 blocks/CU.
// attn-out redistribution overlays the dead q/k/sim/p buffers.
__global__ __launch_bounds__(512, 4)
void wmsa_mfma(const float* __restrict__ x,
               const float* __restrict__ b_qkv,
               const float* __restrict__ rel_pos,
               const float* __restrict__ b_out,
               const unsigned short* __restrict__ ws,
               float* __restrict__ out)
{
    __shared__ __align__(16) unsigned char lds_raw[65536];
    ush   (*qS)[40]  = (ush  (*)[40])(lds_raw + 0);       //  5120 B
    ush   (*qL)[40]  = (ush  (*)[40])(lds_raw + 5120);    //  5120
    ush   (*kS)[40]  = (ush  (*)[40])(lds_raw + 10240);   //  5120
    ush   (*kL)[40]  = (ush  (*)[40])(lds_raw + 15360);   //  5120
    ush   (*vS)[72]  = (ush  (*)[72])(lds_raw + 20480);   //  4608  (v transposed [d][pix])
    ush   (*vL)[72]  = (ush  (*)[72])(lds_raw + 25088);   //  4608
    float (*simb)[68]= (float(*)[68])(lds_raw + 29696);   // 17408
    ush   (*pS)[72]  = (ush  (*)[72])(lds_raw + 47104);   //  9216
    ush   (*pL)[72]  = (ush  (*)[72])(lds_raw + 56320);   //  9216 -> end 65536
    // overlay (valid only after last PV barrier):
    ush   (*aH)[200] = (ush  (*)[200])(lds_raw + 0);      // 25600
    ush   (*aL)[200] = (ush  (*)[200])(lds_raw + 25600);  // 25600 -> end 51200

    const unsigned short* wqh = ws;
    const unsigned short* wql = ws + 110592;
    const unsigned short* woh = ws + 221184;
    const unsigned short* wol = ws + 258048;

    const int t   = threadIdx.x;
    const int blk = blockIdx.x;
    const int b   = blk >> 10;
    const int w   = blk & 1023;
    const int wy  = w >> 5;
    const int wx  = w & 31;

    const int l   = t & 63;
    const int wv  = t >> 6;        // wave 0..7
    const int l15 = l & 15;
    const int lhi = l >> 4;        // 0..3
    const int g   = wv & 1;
    const int mt  = wv >> 1;       // pixel-tile 0..3

    // ---- load this lane's x A-fragments straight from global (rolled) ----
    bf16x8 xh[6], xl[6];
    {
        const int pix = mt * 16 + l15;
        const int py = pix >> 3, px = pix & 7;
        const int sy = (wy * WSZ + py + SHIFT) & 255;
        const int sx = (wx * WSZ + px + SHIFT) & 255;
        const float* xp = x + (((size_t)b * HP + sy) * WP + sx) * CH;
        #pragma unroll
        for (int kc = 0; kc < 6; ++kc) {
            float4 a0 = *(const float4*)(xp + kc * 32 + lhi * 8);
            float4 a1 = *(const float4*)(xp + kc * 32 + lhi * 8 + 4);
            float f[8] = {a0.x, a0.y, a0.z, a0.w, a1.x, a1.y, a1.z, a1.w};
            bf16x8 hi, lo;
            #pragma unroll
            for (int j = 0; j < 8; ++j) {
                unsigned short hh = f2bf(f[j]);
                hi[j] = (short)hh;
                lo[j] = (short)f2bf(f[j] - bf2f(hh));
            }
            xh[kc] = hi;
            xl[kc] = lo;
        }
    }

    const bool edgeY = (wy == 31);
    const bool edgeX = (wx == 31);
    const f32x4 zero4 = {0.f, 0.f, 0.f, 0.f};

    f32x4 att[NH];                 // PV results stashed in regs (head loop unrolled)

    #pragma unroll
    for (int h = 0; h < NH; ++h) {
        // ======== QKV: x(regs) @ wqT -> q,k (row-major) & v (transposed) ========
        {
            f32x4 acc[3] = {zero4, zero4, zero4};
            int wr[3]; int cl[3]; bool isv[3];
            #pragma unroll
            for (int tl = 0; tl < 3; ++tl) {
                int nl = g * 3 + tl;                      // 0..5: q0 q1 k0 | k1 v0 v1
                if (nl < 2)      { wr[tl] = h * 32 + nl * 16;             cl[tl] = nl * 16;       isv[tl] = false; }
                else if (nl < 4) { wr[tl] = 192 + h * 32 + (nl - 2) * 16; cl[tl] = (nl - 2) * 16; isv[tl] = false; }
                else             { wr[tl] = 384 + h * 32 + (nl - 4) * 16; cl[tl] = (nl - 4) * 16; isv[tl] = true;  }
            }
            #pragma unroll
            for (int kc = 0; kc < 6; ++kc) {
                bf16x8 axh = xh[kc];
                bf16x8 axl = xl[kc];
                #pragma unroll
                for (int tl = 0; tl < 3; ++tl) {
                    size_t wo = (size_t)(wr[tl] + l15) * 192 + kc * 32 + lhi * 8;
                    bf16x8 bwh = *(const bf16x8*)&wqh[wo];
                    bf16x8 bwl = *(const bf16x8*)&wql[wo];
                    if (!isv[tl]) {            // q/k swapped: C row = out-ch, col = pixel
                        acc[tl] = MFMA(bwh, axh, acc[tl], 0, 0, 0);
                        acc[tl] = MFMA(bwl, axh, acc[tl], 0, 0, 0);
                        acc[tl] = MFMA(bwh, axl, acc[tl], 0, 0, 0);
                    } else {                   // v normal: C row = pixel, col = d
                        acc[tl] = MFMA(axh, bwh, acc[tl], 0, 0, 0);
                        acc[tl] = MFMA(axl, bwh, acc[tl], 0, 0, 0);
                        acc[tl] = MFMA(axh, bwl, acc[tl], 0, 0, 0);
                    }
                }
            }
            #pragma unroll
            for (int tl = 0; tl < 3; ++tl) {
                int nl = g * 3 + tl;
                if (!isv[tl]) {
                    int pix = mt * 16 + l15;
                    int c0  = cl[tl] + lhi * 4;                        // 4 consecutive channels
                    int jb  = (nl < 2 ? h * 32 : 192 + h * 32) + c0;
                    const f32x4 bias = *(const f32x4*)&b_qkv[jb];
                    u16x4 hi, lo;
                    #pragma unroll
                    for (int r = 0; r < 4; ++r) {
                        float v = acc[tl][r] + bias[r];
                        unsigned short hh = f2bf(v);
                        hi[r] = hh; lo[r] = f2bf(v - bf2f(hh));
                    }
                    if (nl < 2) { *(u16x4*)&qS[pix][c0] = hi; *(u16x4*)&qL[pix][c0] = lo; }
                    else        { *(u16x4*)&kS[pix][c0] = hi; *(u16x4*)&kL[pix][c0] = lo; }
                } else {
                    int d    = cl[tl] + l15;
                    int pix0 = mt * 16 + lhi * 4;                      // 4 consecutive pixels
                    float bv = b_qkv[384 + h * 32 + d];
                    u16x4 hi, lo;
                    #pragma unroll
                    for (int r = 0; r < 4; ++r) {
                        float v = acc[tl][r] + bv;
                        unsigned short hh = f2bf(v);
                        hi[r] = hh; lo[r] = f2bf(v - bf2f(hh));
                    }
                    *(u16x4*)&vS[d][pix0] = hi;
                    *(u16x4*)&vL[d][pix0] = lo;
                }
            }
        }
        __syncthreads();

        // ======== QK^T (swapped: arg1=k -> 4 consecutive key cols per lane) ========
        {
            bf16x8 aqh = *(const bf16x8*)&qS[mt * 16 + l15][lhi * 8];
            bf16x8 aql = *(const bf16x8*)&qL[mt * 16 + l15][lhi * 8];
            #pragma unroll
            for (int k2 = 0; k2 < 2; ++k2) {
                int kt = g * 2 + k2;
                bf16x8 bkh = *(const bf16x8*)&kS[kt * 16 + l15][lhi * 8];
                bf16x8 bkl = *(const bf16x8*)&kL[kt * 16 + l15][lhi * 8];
                f32x4 s = zero4;
                s = MFMA(bkh, aqh, s, 0, 0, 0);
                s = MFMA(bkl, aqh, s, 0, 0, 0);
                s = MFMA(bkh, aql, s, 0, 0, 0);
                *(f32x4*)&simb[mt * 16 + l15][kt * 16 + lhi * 4] = s;  // float4 write
            }
        }
        __syncthreads();

        // ======== softmax + bias + shift-mask (proven fp32 path) ========
        {
            const int p  = t >> 3;
            const int qb = (t & 7) * 8;
            const int py = p >> 3, px = p & 7;
            float s[8];
            f32x4 s0 = *(const f32x4*)&simb[p][qb];
            f32x4 s1 = *(const f32x4*)&simb[p][qb + 4];
            #pragma unroll
            for (int i = 0; i < 4; ++i) { s[i] = s0[i]; s[i + 4] = s1[i]; }
            #pragma unroll
            for (int i = 0; i < 8; ++i) {
                int q  = qb + i;
                int qy = q >> 3, qx = q & 7;
                float val = s[i] * SCALE + rel_pos[h * 225 + (py - qy + 7) * 15 + (px - qx + 7)];
                bool msk = (edgeY && ((py < SHIFT) != (qy < SHIFT))) ||
                           (edgeX && ((px < SHIFT) != (qx < SHIFT)));
                s[i] = msk ? -1e30f : val;
            }
            float m = s[0];
            #pragma unroll
            for (int i = 1; i < 8; ++i) m = fmaxf(m, s[i]);
            #pragma unroll
            for (int off = 1; off < 8; off <<= 1) m = fmaxf(m, __shfl_xor(m, off));
            float sum = 0.f;
            #pragma unroll
            for (int i = 0; i < 8; ++i) { s[i] = __expf(s[i] - m); sum += s[i]; }
            #pragma unroll
            for (int off = 1; off < 8; off <<= 1) sum += __shfl_xor(sum, off);
            float inv = 1.f / sum;
            u16x8 hi, lo;
            #pragma unroll
            for (int i = 0; i < 8; ++i) {
                float pv = s[i] * inv;
                unsigned short hh = f2bf(pv);
                hi[i] = hh; lo[i] = f2bf(pv - bf2f(hh));
            }
            *(u16x8*)&pS[p][qb] = hi;                                  // b128 write
            *(u16x8*)&pL[p][qb] = lo;
        }
        __syncthreads();

        // ======== PV (swapped: arg1=vT -> C row=d, col=pixel) -> stash in regs ====
        {
            f32x4 pa = zero4;
            #pragma unroll
            for (int kc = 0; kc < 2; ++kc) {
                bf16x8 avh = *(const bf16x8*)&vS[g * 16 + l15][kc * 32 + lhi * 8];
                bf16x8 avl = *(const bf16x8*)&vL[g * 16 + l15][kc * 32 + lhi * 8];
                bf16x8 bph = *(const bf16x8*)&pS[mt * 16 + l15][kc * 32 + lhi * 8];
                bf16x8 bpl = *(const bf16x8*)&pL[mt * 16 + l15][kc * 32 + lhi * 8];
                pa = MFMA(avh, bph, pa, 0, 0, 0);
                pa = MFMA(avl, bph, pa, 0, 0, 0);
                pa = MFMA(avh, bpl, pa, 0, 0, 0);
            }
            att[h] = pa;
        }
        __syncthreads();           // protects q/k/v/sim/p reuse; last iter frees overlay
    }

    // ---- attn-out -> overlay LDS (q/k/sim/p dead), split hi/lo ----
    {
        int pix = mt * 16 + l15;
        #pragma unroll
        for (int h = 0; h < NH; ++h) {
            int c0 = h * 32 + g * 16 + lhi * 4;
            u16x4 hi, lo;
            #pragma unroll
            for (int r = 0; r < 4; ++r) {
                float v = att[h][r];
                unsigned short hh = f2bf(v);
                hi[r] = hh; lo[r] = f2bf(v - bf2f(hh));
            }
            *(u16x4*)&aH[pix][c0] = hi;
            *(u16x4*)&aL[pix][c0] = lo;
        }
    }
    __syncthreads();

    // ======== output projection (swapped) + inverse-roll scatter ========
    {
        f32x4 po[6];
        #pragma unroll
        for (int i = 0; i < 6; ++i) po[i] = zero4;
        #pragma unroll
        for (int kc = 0; kc < 6; ++kc) {
            bf16x8 bxh = *(const bf16x8*)&aH[mt * 16 + l15][kc * 32 + lhi * 8];
            bf16x8 bxl = *(const bf16x8*)&aL[mt * 16 + l15][kc * 32 + lhi * 8];
            #pragma unroll
            for (int tn = 0; tn < 6; ++tn) {
                int nt = g + 2 * tn;
                size_t wo = (size_t)(nt * 16 + l15) * 192 + kc * 32 + lhi * 8;
                bf16x8 awh = *(const bf16x8*)&woh[wo];
                bf16x8 awl = *(const bf16x8*)&wol[wo];
                po[tn] = MFMA(awh, bxh, po[tn], 0, 0, 0);
                po[tn] = MFMA(awl, bxh, po[tn], 0, 0, 0);
                po[tn] = MFMA(awh, bxl, po[tn], 0, 0, 0);
            }
        }
        int pix = mt * 16 + l15;
        int py = pix >> 3, px = pix & 7;
        int sy = (wy * WSZ + py + SHIFT) & 255;
        int sx = (wx * WSZ + px + SHIFT) & 255;
        float* dst = out + (((size_t)b * HP + sy) * WP + sx) * CH;
        #pragma unroll
        for (int tn = 0; tn < 6; ++tn) {
            int nt = g + 2 * tn;
            int c0 = nt * 16 + lhi * 4;
            f32x4 r = po[tn];
            const f32x4 bb = *(const f32x4*)&b_out[c0];
            r += bb;
            *(f32x4*)&dst[c0] = r;                                     // dwordx4 store
        }
    }
}

extern "C" void kernel_launch(void* const* d_in, const int* in_sizes, int n_in,
                              void* d_out, int out_size, void* d_ws, size_t ws_size,
                              hipStream_t stream) {
    const float* x       = (const float*)d_in[0];
    const float* w_qkv   = (const float*)d_in[1];
    const float* b_qkv   = (const float*)d_in[2];
    const float* rel_pos = (const float*)d_in[3];
    const float* w_out   = (const float*)d_in[4];
    const float* b_out   = (const float*)d_in[5];
    unsigned short* ws   = (unsigned short*)d_ws;   // needs 589824 B

    wprep<<<dim3(576), dim3(256), 0, stream>>>(w_qkv, w_out, ws);
    wmsa_mfma<<<dim3(8192), dim3(512), 0, stream>>>(
        x, b_qkv, rel_pos, b_out, ws, (float*)d_out);
}